// Round 13
// baseline (21.937 us; speedup 1.0000x reference)
//
#include <hip/hip_runtime.h>

// Problem constants (from reference)
#define HH 96
#define WW 96
#define CH 64
#define NHEADS 4
#define DHEAD 16
#define BATCH 2
#define PLANE (HH * WW)

// MFMA row-tile geometry: block = 6 waves; wave = 1 row x 16 positions.
// Grid = 8 slabs x 96 tiles = 768 blocks = EXACTLY 3 blocks/CU (no tail).
// REP=2 DIAGNOSTIC: body executed twice (2nd pass L2-warm, same output) to
// decompose dur = fixed + work_cold + work_warm across rounds.
#define REP 2
#define BROWS 6
#define BCOLS 16
#define HROWS (BROWS + 6)       // 12 halo rows
#define HCOLS (BCOLS + 6)       // 22 halo cols
#define KPITCH 20               // halfs per halo pixel in k_lds (16 + 4 pad)
#define KPIX (HROWS * HCOLS)    // 264
#define KPIXA (KPIX + 10)       // 274: zero tail covers A2 fragment overrun
#define VPITCH 24               // halfs per halo row in v_lds (22 + 2 zero pad)
#define VCH (HROWS * VPITCH + 8)// 296 halfs per channel (+8 zero tail)
#define TY_N (HH / BROWS)       // 16
#define TX_N (WW / BCOLS)       // 6

typedef _Float16 half4 __attribute__((ext_vector_type(4)));
typedef float f32x4 __attribute__((ext_vector_type(4)));
typedef _Float16 h2 __attribute__((ext_vector_type(2)));
union H2U { unsigned int u; h2 h; };

template <bool INTERIOR>
__device__ __forceinline__ void block_body(
    const float* __restrict__ q, const float* __restrict__ k,
    const float* __restrict__ v, float* __restrict__ out,
    _Float16* __restrict__ lk, _Float16* __restrict__ lv,
    int c0, int h0, int w0)
{
    const int tid = threadIdx.x;        // 0..383

    // ---- q fragment first (overlaps staging latency) ----
    const int lane = tid & 63;
    const int wid  = tid >> 6;          // 0..5
    const int lp   = lane & 15;
    const int lg   = lane >> 4;
    const int h    = h0 + wid;

    const float QS = 0.25f * 1.4426950408889634f;  // 1/sqrt(16) * log2(e)
    const int qbase = (c0 + lg * 4) * PLANE + h * WW + w0 + lp;
    half4 qf;
    qf.x = (_Float16)(q[qbase] * QS);
    qf.y = (_Float16)(q[qbase + PLANE] * QS);
    qf.z = (_Float16)(q[qbase + 2 * PLANE] * QS);
    qf.w = (_Float16)(q[qbase + 3 * PLANE] * QS);

    // ---- hoisted band/edge masks (loop-invariant) ----
    bool ok1[4], ok2[4];
#pragma unroll
    for (int e = 0; e < 4; ++e) {
        const int j1 = lg * 4 + e;
        const int j2 = 16 + j1;
        ok1[e] = ((unsigned)(j1 - lp) < 7u);     // band: j in [p, p+6]
        ok2[e] = ((unsigned)(j2 - lp) < 7u);
        if constexpr (!INTERIOR) {
            ok1[e] = ok1[e] && ((unsigned)(w0 - 3 + j1) < (unsigned)WW);
            ok2[e] = ok2[e] && ((unsigned)(w0 - 3 + j2) < (unsigned)WW);
        }
    }

    for (int rep = 0; rep < REP; ++rep) {
        if (rep) __syncthreads();   // LDS reuse hazard between passes

        // ---- K staging: span = (row, ch-pair); 32 lanes sweep 22 cols ----
        {
            const int col = tid & 31;
            const int sp0 = tid >> 5;          // 0..11
#pragma unroll 2
            for (int r = 0; r < 8; ++r) {
                const int sid = r * 12 + sp0;  // 0..95
                const int row = sid >> 3;
                const int cp  = sid & 7;
                if (col < HCOLS) {
                    int gh = h0 - 3 + row;
                    int gw = w0 - 3 + col;
                    if constexpr (!INTERIOR) {
                        gh = min(max(gh, 0), HH - 1);
                        gw = min(max(gw, 0), WW - 1);
                    }
                    const float* p0 = k + (size_t)(c0 + cp * 2) * PLANE + gh * WW + gw;
                    H2U t;
                    t.h.x = (_Float16)p0[0];
                    t.h.y = (_Float16)p0[PLANE];
                    *(h2*)&lk[(row * HCOLS + col) * KPITCH + cp * 2] = t.h;
                }
            }
        }

        // ---- V staging: span = (row, ch); 16 lanes x 2 contiguous cols ----
        {
            const int l16  = tid & 15;
            const int sq0  = tid >> 4;         // 0..23
            const int col0 = l16 * 2;
#pragma unroll 2
            for (int r = 0; r < 8; ++r) {
                const int sid = r * 24 + sq0;  // 0..191
                const int row = sid >> 4;
                const int ch  = sid & 15;
                if (col0 <= HCOLS) {           // cols 0..21 data; 22 -> zero pad
                    H2U t;
                    if (col0 < HCOLS) {
                        int gh = h0 - 3 + row;
                        int ga = w0 - 3 + col0;
                        int gb = ga + 1;
                        if constexpr (!INTERIOR) {
                            gh = min(max(gh, 0), HH - 1);
                            ga = min(max(ga, 0), WW - 1);
                            gb = min(max(gb, 0), WW - 1);
                        }
                        const float* p0 = v + (size_t)(c0 + ch) * PLANE + gh * WW;
                        t.h.x = (_Float16)p0[ga];
                        t.h.y = (_Float16)p0[gb];
                    } else {
                        t.u = 0;               // pad cols 22,23
                    }
                    *(h2*)&lv[ch * VCH + row * VPITCH + col0] = t.h;
                }
            }
        }

        // ---- zero tails (read by A2 fragments; must be finite) ----
        {
            H2U z; z.u = 0;
            if (tid < 100)                      // K pixels 264..273 (200 halfs)
                *(h2*)&lk[KPIX * KPITCH + tid * 2] = z.h;
            if (tid < 64)                       // V per-channel tail halfs 288..295
                *(h2*)&lv[(tid >> 2) * VCH + 288 + (tid & 3) * 2] = z.h;
        }
        __syncthreads();

        // ---- compute: wave wid -> row h0+wid, positions w0..w0+15 ----
        f32x4 acc = {0.f, 0.f, 0.f, 0.f};
        float ssA = 0.f, ssB = 0.f;

#pragma unroll
        for (int dy = 0; dy < 7; ++dy) {
            if constexpr (!INTERIOR) {
                if ((unsigned)(h + dy - 3) >= (unsigned)HH) continue;  // invalid row
            }
            const int r = wid + dy;                    // halo row index

            // QK: S^T[j][p] = K_pix[j][c] x Q[c][p]
            const half4 ka1 = *(const half4*)&lk[(r * HCOLS + lp) * KPITCH + lg * 4];
            const half4 ka2 = *(const half4*)&lk[(r * HCOLS + 16 + lp) * KPITCH + lg * 4];
            const f32x4 zz = {0.f, 0.f, 0.f, 0.f};
            f32x4 s1 = __builtin_amdgcn_mfma_f32_16x16x16f16(ka1, qf, zz, 0, 0, 0);
            f32x4 s2 = __builtin_amdgcn_mfma_f32_16x16x16f16(ka2, qf, zz, 0, 0, 0);

            // masked exp2 -> P fragments (C layout == B layout: direct feed)
            half4 p1, p2;
#pragma unroll
            for (int e = 0; e < 4; ++e) {
                const float e1 = ok1[e] ? __builtin_amdgcn_exp2f(s1[e]) : 0.f;
                const float e2 = ok2[e] ? __builtin_amdgcn_exp2f(s2[e]) : 0.f;
                ssA += e1;
                ssB += e2;
                p1[e] = (_Float16)e1;
                p2[e] = (_Float16)e2;
            }

            // PV: out^T[c][p] += V^T[c][j] x P[j][p]
            const half4 va1 = *(const half4*)&lv[lp * VCH + r * VPITCH + lg * 4];
            const half4 va2 = *(const half4*)&lv[lp * VCH + r * VPITCH + 16 + lg * 4];
            acc = __builtin_amdgcn_mfma_f32_16x16x16f16(va1, p1, acc, 0, 0, 0);
            acc = __builtin_amdgcn_mfma_f32_16x16x16f16(va2, p2, acc, 0, 0, 0);
        }

        // softmax denominator: reduce partial sums across the 4 lane-groups
        float ssum = ssA + ssB;
        ssum += __shfl_xor(ssum, 16, 64);
        ssum += __shfl_xor(ssum, 32, 64);
        const float inv = 1.0f / ssum;

        // store: C rows c = lg*4 + e, col p = lp
        const int obase = (c0 + lg * 4) * PLANE + h * WW + w0 + lp;
#pragma unroll
        for (int e = 0; e < 4; ++e)
            out[obase + e * PLANE] = acc[e] * inv;
    }
}

__global__ __launch_bounds__(384)
__attribute__((amdgpu_waves_per_eu(8)))
void natten_mfma6_r2(
    const float* __restrict__ q, const float* __restrict__ k,
    const float* __restrict__ v, float* __restrict__ out)
{
    __shared__ __align__(16) _Float16 lk[KPIXA * KPITCH];  // 10,960 B
    __shared__ __align__(16) _Float16 lv[16 * VCH];        //  9,472 B

    const int bid  = (int)blockIdx.x;
    const int slab = bid & 7;               // one (b,head) per XCD
    const int t    = bid >> 3;              // 0..95
    const int b = slab >> 2, head = slab & 3;
    const int ty = t / TX_N, tx = t % TX_N;
    const int c0 = b * CH + head * DHEAD;
    const int h0 = ty * BROWS, w0 = tx * BCOLS;

    const bool interior = (ty >= 1) && (ty <= TY_N - 2) &&
                          (tx >= 1) && (tx <= TX_N - 2);
    if (interior)
        block_body<true >(q, k, v, out, lk, lv, c0, h0, w0);
    else
        block_body<false>(q, k, v, out, lk, lv, c0, h0, w0);
}

extern "C" void kernel_launch(void* const* d_in, const int* in_sizes, int n_in,
                              void* d_out, int out_size, void* d_ws, size_t ws_size,
                              hipStream_t stream) {
    const float* q = (const float*)d_in[0];
    const float* k = (const float*)d_in[1];
    const float* v = (const float*)d_in[2];
    float* out = (float*)d_out;

    const int grid = BATCH * NHEADS * TY_N * TX_N;   // 768
    natten_mfma6_r2<<<grid, 384, 0, stream>>>(q, k, v, out);
}

// Round 15
// 14.914 us; speedup vs baseline: 1.4709x; 1.4709x over previous
//
#include <hip/hip_runtime.h>

// Problem constants (from reference)
#define HH 96
#define WW 96
#define CH 64
#define NHEADS 4
#define DHEAD 16
#define BATCH 2
#define PLANE (HH * WW)

// MFMA row-tile geometry: block = 6 waves; wave = 1 row x 16 positions.
// Grid = 8 slabs x 96 tiles = 768 blocks = EXACTLY 3 blocks/CU (no tail).
// Halo cols widened to 24 (global w0-4 .. w0+19, even-aligned) so staging
// is pure float2 loads; extra cols are killed by the band mask.
#define BROWS 6
#define BCOLS 16
#define HROWS (BROWS + 6)        // 12 halo rows
#define HCOLS 24                 // halo cols (even-aligned)
#define KPITCH 20                // halfs per halo pixel in k_lds (16 + 4 pad)
#define KPIX (HROWS * HCOLS)     // 288
#define KPIXA (KPIX + 8)         // 296: zero tail covers A2 fragment overrun
#define VPITCH HCOLS             // 24 halfs per halo row in v_lds
#define VCH (HROWS * VPITCH + 8) // 296 halfs per channel (+8 zero tail)
#define TY_N (HH / BROWS)        // 16
#define TX_N (WW / BCOLS)        // 6

typedef _Float16 half4 __attribute__((ext_vector_type(4)));
typedef _Float16 h2 __attribute__((ext_vector_type(2)));
typedef float f32x4 __attribute__((ext_vector_type(4)));

__device__ __forceinline__ half4 pack4(float a, float b, float c, float d) {
#if __has_builtin(__builtin_amdgcn_cvt_pkrtz)
    h2 lo = __builtin_bit_cast(h2, __builtin_amdgcn_cvt_pkrtz(a, b));
    h2 hi = __builtin_bit_cast(h2, __builtin_amdgcn_cvt_pkrtz(c, d));
    half4 r; r.x = lo.x; r.y = lo.y; r.z = hi.x; r.w = hi.y;
    return r;
#else
    half4 r; r.x = (_Float16)a; r.y = (_Float16)b;
    r.z = (_Float16)c; r.w = (_Float16)d;
    return r;
#endif
}

template <bool INTERIOR>
__device__ __forceinline__ void block_body(
    const float* __restrict__ q, const float* __restrict__ k,
    const float* __restrict__ v, float* __restrict__ out,
    _Float16* __restrict__ lk, _Float16* __restrict__ lv,
    int c0, int h0, int w0)
{
    const int tid = threadIdx.x;        // 0..383

    // ---- q fragment first (overlaps staging latency) ----
    const int lane = tid & 63;
    const int wid  = tid >> 6;          // 0..5
    const int lp   = lane & 15;
    const int lg   = lane >> 4;
    const int h    = h0 + wid;

    const float QS = 0.25f * 1.4426950408889634f;  // 1/sqrt(16) * log2(e)
    const int qbase = (c0 + lg * 4) * PLANE + h * WW + w0 + lp;
    half4 qf;
    qf.x = (_Float16)(q[qbase] * QS);
    qf.y = (_Float16)(q[qbase + PLANE] * QS);
    qf.z = (_Float16)(q[qbase + 2 * PLANE] * QS);
    qf.w = (_Float16)(q[qbase + 3 * PLANE] * QS);

    // ---- staging: span = (tensor,row,ch); 16-lane group sweeps 24 cols ----
    // 192 spans/tensor = 12 rows x 16 ch; 24 groups -> 8 rounds/tensor.
    // Lane l16 covers halo cols {2*l16, 2*l16+1}; active lanes 0..11.
    const int l16  = tid & 15;
    const int grp  = tid >> 4;          // 0..23
    const int col0 = l16 * 2;           // 0..30
    const bool act = (col0 < HCOLS);

    if constexpr (INTERIOR) {
        // Batched float2 staging: 8 loads in flight, then convert+write.
        float2 kb[8];
#pragma unroll
        for (int r = 0; r < 8; ++r) {
            const int sid = r * 24 + grp;
            const int row = sid >> 4, ch = sid & 15;
            if (act)
                kb[r] = *(const float2*)(k + (size_t)(c0 + ch) * PLANE +
                                         (h0 - 3 + row) * WW + (w0 - 4) + col0);
        }
#pragma unroll
        for (int r = 0; r < 8; ++r) {
            const int sid = r * 24 + grp;
            const int row = sid >> 4, ch = sid & 15;
            if (act) {
                const int pix = row * HCOLS + col0;
                lk[pix * KPITCH + ch]       = (_Float16)kb[r].x;
                lk[(pix + 1) * KPITCH + ch] = (_Float16)kb[r].y;
            }
        }
        float2 vb[8];
#pragma unroll
        for (int r = 0; r < 8; ++r) {
            const int sid = r * 24 + grp;
            const int row = sid >> 4, ch = sid & 15;
            if (act)
                vb[r] = *(const float2*)(v + (size_t)(c0 + ch) * PLANE +
                                         (h0 - 3 + row) * WW + (w0 - 4) + col0);
        }
#pragma unroll
        for (int r = 0; r < 8; ++r) {
            const int sid = r * 24 + grp;
            const int row = sid >> 4, ch = sid & 15;
            if (act) {
                h2 t; t.x = (_Float16)vb[r].x; t.y = (_Float16)vb[r].y;
                *(h2*)&lv[ch * VCH + row * VPITCH + col0] = t;
            }
        }
    } else {
        // Edge blocks: scalar clamped staging (edge tiles only).
#pragma unroll
        for (int r = 0; r < 8; ++r) {
            const int sid = r * 24 + grp;
            const int row = sid >> 4, ch = sid & 15;
            if (act) {
                const int gh = min(max(h0 - 3 + row, 0), HH - 1);
                const int ga = min(max(w0 - 4 + col0, 0), WW - 1);
                const int gb = min(max(w0 - 3 + col0, 0), WW - 1);
                const float* p0 = k + (size_t)(c0 + ch) * PLANE + gh * WW;
                const int pix = row * HCOLS + col0;
                lk[pix * KPITCH + ch]       = (_Float16)p0[ga];
                lk[(pix + 1) * KPITCH + ch] = (_Float16)p0[gb];
            }
        }
#pragma unroll
        for (int r = 0; r < 8; ++r) {
            const int sid = r * 24 + grp;
            const int row = sid >> 4, ch = sid & 15;
            if (act) {
                const int gh = min(max(h0 - 3 + row, 0), HH - 1);
                const int ga = min(max(w0 - 4 + col0, 0), WW - 1);
                const int gb = min(max(w0 - 3 + col0, 0), WW - 1);
                const float* p0 = v + (size_t)(c0 + ch) * PLANE + gh * WW;
                h2 t; t.x = (_Float16)p0[ga]; t.y = (_Float16)p0[gb];
                *(h2*)&lv[ch * VCH + row * VPITCH + col0] = t;
            }
        }
    }

    // ---- zero tails (read by A2 fragments; must be finite) ----
    {
        h2 z; z.x = (_Float16)0.f; z.y = (_Float16)0.f;
        if (tid < 80)                       // K pixels 288..295 (160 halfs)
            *(h2*)&lk[KPIX * KPITCH + tid * 2] = z;
        if (tid < 64)                       // V per-channel tail halfs 288..295
            *(h2*)&lv[(tid >> 2) * VCH + HROWS * VPITCH + (tid & 3) * 2] = z;
    }
    __syncthreads();

    // ---- band/edge masks (post-staging to cut staging reg pressure) ----
    // halo col j <-> dx = j - lp - 4; valid iff j - lp in [1,7]
    bool ok1[4], ok2[4];
#pragma unroll
    for (int e = 0; e < 4; ++e) {
        const int j1 = lg * 4 + e;
        const int j2 = 16 + j1;
        ok1[e] = ((unsigned)(j1 - lp - 1) < 7u);
        ok2[e] = ((unsigned)(j2 - lp - 1) < 7u);
        if constexpr (!INTERIOR) {
            ok1[e] = ok1[e] && ((unsigned)(w0 - 4 + j1) < (unsigned)WW);
            ok2[e] = ok2[e] && ((unsigned)(w0 - 4 + j2) < (unsigned)WW);
        }
    }

    // ---- compute: wave wid -> row h0+wid, positions w0..w0+15 ----
    f32x4 accA = {0.f, 0.f, 0.f, 0.f};
    f32x4 accB = {0.f, 0.f, 0.f, 0.f};
    float ssA = 0.f, ssB = 0.f;

#pragma unroll
    for (int dy = 0; dy < 7; ++dy) {
        if constexpr (!INTERIOR) {
            if ((unsigned)(h + dy - 3) >= (unsigned)HH) continue;  // invalid row
        }
        const int r = wid + dy;                    // halo row index

        // QK: S^T[j][p] = K_pix[j][c] x Q[c][p]
        const half4 ka1 = *(const half4*)&lk[(r * HCOLS + lp) * KPITCH + lg * 4];
        const half4 ka2 = *(const half4*)&lk[(r * HCOLS + 16 + lp) * KPITCH + lg * 4];
        const f32x4 zz = {0.f, 0.f, 0.f, 0.f};
        f32x4 s1 = __builtin_amdgcn_mfma_f32_16x16x16f16(ka1, qf, zz, 0, 0, 0);
        f32x4 s2 = __builtin_amdgcn_mfma_f32_16x16x16f16(ka2, qf, zz, 0, 0, 0);

        // masked exp2 -> P fragments (C layout == B layout: direct feed)
        const float e10 = ok1[0] ? __builtin_amdgcn_exp2f(s1[0]) : 0.f;
        const float e11 = ok1[1] ? __builtin_amdgcn_exp2f(s1[1]) : 0.f;
        const float e12 = ok1[2] ? __builtin_amdgcn_exp2f(s1[2]) : 0.f;
        const float e13 = ok1[3] ? __builtin_amdgcn_exp2f(s1[3]) : 0.f;
        const float e20 = ok2[0] ? __builtin_amdgcn_exp2f(s2[0]) : 0.f;
        const float e21 = ok2[1] ? __builtin_amdgcn_exp2f(s2[1]) : 0.f;
        const float e22 = ok2[2] ? __builtin_amdgcn_exp2f(s2[2]) : 0.f;
        const float e23 = ok2[3] ? __builtin_amdgcn_exp2f(s2[3]) : 0.f;
        ssA += (e10 + e11) + (e12 + e13);
        ssB += (e20 + e21) + (e22 + e23);
        const half4 p1 = pack4(e10, e11, e12, e13);
        const half4 p2 = pack4(e20, e21, e22, e23);

        // PV: out^T[c][p] += V^T[c][j] x P[j][p]  (dual acc: halved chain)
        const half4 va1 = *(const half4*)&lv[lp * VCH + r * VPITCH + lg * 4];
        const half4 va2 = *(const half4*)&lv[lp * VCH + r * VPITCH + 16 + lg * 4];
        accA = __builtin_amdgcn_mfma_f32_16x16x16f16(va1, p1, accA, 0, 0, 0);
        accB = __builtin_amdgcn_mfma_f32_16x16x16f16(va2, p2, accB, 0, 0, 0);
    }

    // softmax denominator: reduce partial sums across the 4 lane-groups
    float ssum = ssA + ssB;
    ssum += __shfl_xor(ssum, 16, 64);
    ssum += __shfl_xor(ssum, 32, 64);
    const float inv = 1.0f / ssum;

    const f32x4 acc = accA + accB;

    // store: C rows c = lg*4 + e, col p = lp -> 4-segment coalesced
    const int obase = (c0 + lg * 4) * PLANE + h * WW + w0 + lp;
#pragma unroll
    for (int e = 0; e < 4; ++e)
        out[obase + e * PLANE] = acc[e] * inv;
}

__global__ __launch_bounds__(384)
__attribute__((amdgpu_waves_per_eu(5)))
void natten_mfma6b(
    const float* __restrict__ q, const float* __restrict__ k,
    const float* __restrict__ v, float* __restrict__ out)
{
    __shared__ __align__(16) _Float16 lk[KPIXA * KPITCH];  // 11,840 B
    __shared__ __align__(16) _Float16 lv[16 * VCH];        //  9,472 B

    const int bid  = (int)blockIdx.x;
    const int slab = bid & 7;               // one (b,head) per XCD
    const int t    = bid >> 3;              // 0..95
    const int b = slab >> 2, head = slab & 3;
    const int ty = t / TX_N, tx = t % TX_N;
    const int c0 = b * CH + head * DHEAD;
    const int h0 = ty * BROWS, w0 = tx * BCOLS;

    const bool interior = (ty >= 1) && (ty <= TY_N - 2) &&
                          (tx >= 1) && (tx <= TX_N - 2);
    if (interior)
        block_body<true >(q, k, v, out, lk, lv, c0, h0, w0);
    else
        block_body<false>(q, k, v, out, lk, lv, c0, h0, w0);
}

extern "C" void kernel_launch(void* const* d_in, const int* in_sizes, int n_in,
                              void* d_out, int out_size, void* d_ws, size_t ws_size,
                              hipStream_t stream) {
    const float* q = (const float*)d_in[0];
    const float* k = (const float*)d_in[1];
    const float* v = (const float*)d_in[2];
    float* out = (float*)d_out;

    const int grid = BATCH * NHEADS * TY_N * TX_N;   // 768
    natten_mfma6b<<<grid, 384, 0, stream>>>(q, k, v, out);
}